// Round 1
// baseline (648.455 us; speedup 1.0000x reference)
//
#include <hip/hip_runtime.h>
#include <cstdint>
#include <cstddef>

typedef unsigned short u16;
typedef __attribute__((ext_vector_type(8))) __bf16 bf16x8;
typedef __attribute__((ext_vector_type(4))) float floatx4;

typedef const __attribute__((address_space(1))) void* gptr_t;
typedef __attribute__((address_space(3))) void* lptr_t;

__device__ __forceinline__ u16 f2b(float f) {
    unsigned u = __builtin_bit_cast(unsigned, f);
    u += 0x7fffu + ((u >> 16) & 1u);   // RNE; inputs are finite
    return (u16)(u >> 16);
}

// ---------------- fp32 -> bf16 cast (vectorized) ----------------
__global__ void cast_f32_bf16(const float* __restrict__ in, u16* __restrict__ out, int n4) {
    int i = blockIdx.x * blockDim.x + threadIdx.x;
    if (i < n4) {
        const float4 v = ((const float4*)in)[i];
        ushort4 o;
        o.x = f2b(v.x); o.y = f2b(v.y); o.z = f2b(v.z); o.w = f2b(v.w);
        ((ushort4*)out)[i] = o;
    }
}

// ---------------- bf16 GEMM, C = A @ B^T + bias ----------------
// A: M x K bf16 row-major.  B: N x K bf16 row-major (i.e. B^T input).
// 128x128 tile, 4 waves (2x2), each wave 4x4 of 16x16x32 MFMA tiles.
// m97 structure: global_load_lds width=16 staging, 2-barrier K-loop.
template <bool OUT_BF16>
__global__ __launch_bounds__(256, 2)
void gemm_bt(const u16* __restrict__ A, const u16* __restrict__ B,
             const float* __restrict__ bias, void* __restrict__ Cout,
             int N, int K)
{
    __shared__ u16 lA[128 * 32];
    __shared__ u16 lB[128 * 32];

    const int tid  = threadIdx.x;
    const int m0   = blockIdx.y * 128;
    const int n0   = blockIdx.x * 128;
    const int row  = tid >> 2;   // 0..63 (staging row; +64 for second half)
    const int chk  = tid & 3;    // 16B chunk within a 64B row
    const int lane = tid & 63;
    const int wv   = tid >> 6;
    const int wm   = wv >> 1;
    const int wn   = wv & 1;
    const int lrow = lane & 15;
    const int quad = lane >> 4;

    const u16* gA0 = A + (size_t)(m0 + row) * K + chk * 8;
    const u16* gB0 = B + (size_t)(n0 + row) * K + chk * 8;
    u16* sA0 = lA + tid * 8;     // per-wave contiguous: base + lane*16B
    u16* sB0 = lB + tid * 8;

    const u16* pA = lA + (wm * 64 + lrow) * 32 + quad * 8;
    const u16* pB = lB + (wn * 64 + lrow) * 32 + quad * 8;

    const floatx4 fzero = {0.f, 0.f, 0.f, 0.f};
    floatx4 acc[4][4];
    #pragma unroll
    for (int i = 0; i < 4; i++)
        #pragma unroll
        for (int j = 0; j < 4; j++) acc[i][j] = fzero;

    const size_t rstride = (size_t)64 * K;

    for (int k0 = 0; k0 < K; k0 += 32) {
        __builtin_amdgcn_global_load_lds((gptr_t)(gA0 + k0),           (lptr_t)sA0,          16, 0, 0);
        __builtin_amdgcn_global_load_lds((gptr_t)(gA0 + rstride + k0), (lptr_t)(sA0 + 2048), 16, 0, 0);
        __builtin_amdgcn_global_load_lds((gptr_t)(gB0 + k0),           (lptr_t)sB0,          16, 0, 0);
        __builtin_amdgcn_global_load_lds((gptr_t)(gB0 + rstride + k0), (lptr_t)(sB0 + 2048), 16, 0, 0);
        __syncthreads();   // compiler emits vmcnt(0) drain before s_barrier

        bf16x8 af[4], bfr[4];
        #pragma unroll
        for (int i = 0; i < 4; i++) {
            af[i]  = *(const bf16x8*)(pA + i * 512);
            bfr[i] = *(const bf16x8*)(pB + i * 512);
        }
        #pragma unroll
        for (int i = 0; i < 4; i++)
            #pragma unroll
            for (int j = 0; j < 4; j++)
                acc[i][j] = __builtin_amdgcn_mfma_f32_16x16x32_bf16(af[i], bfr[j], acc[i][j], 0, 0, 0);
        __syncthreads();
    }

    float bsv[4];
    #pragma unroll
    for (int j = 0; j < 4; j++) bsv[j] = bias[n0 + wn * 64 + j * 16 + lrow];

    #pragma unroll
    for (int i = 0; i < 4; i++) {
        const int mbase = m0 + wm * 64 + i * 16 + quad * 4;
        #pragma unroll
        for (int j = 0; j < 4; j++) {
            const int n = n0 + wn * 64 + j * 16 + lrow;
            #pragma unroll
            for (int r = 0; r < 4; r++) {
                const float v = acc[i][j][r] + bsv[j];
                const size_t idx = (size_t)(mbase + r) * N + n;
                if constexpr (OUT_BF16) ((u16*)Cout)[idx] = f2b(v);
                else                    ((float*)Cout)[idx] = v;
            }
        }
    }
}

// ---------------- per-token head-head attention + scramble ----------------
// One wave per token. QKV row = [q(16x64) | k(16x64) | v(16x64)] bf16.
// E = q @ k^T via two MFMA (K=64); softmax over key-head (16 lanes of a quad);
// Y = A @ v via MFMA with A zero-padded K=16->32; scatter Y into Z in the
// reshape-scrambled layout so the output projection is a plain GEMM.
__global__ __launch_bounds__(256)
void attn(const u16* __restrict__ QKV, u16* __restrict__ Z)
{
    __shared__ u16 sA[4][16 * 32];
    const int lane = threadIdx.x & 63;
    const int wv   = threadIdx.x >> 6;
    const int lrow = lane & 15;
    const int quad = lane >> 4;
    const int tok  = blockIdx.x * 4 + wv;

    const u16* base = QKV + (size_t)tok * 3072;

    // zero the k=16..31 pad of A
    for (int idx = lane; idx < 256; idx += 64)
        sA[wv][(idx >> 4) * 32 + 16 + (idx & 15)] = 0;

    const bf16x8 q0 = *(const bf16x8*)(base + lrow * 64 + quad * 8);
    const bf16x8 q1 = *(const bf16x8*)(base + lrow * 64 + 32 + quad * 8);
    const bf16x8 k0 = *(const bf16x8*)(base + 1024 + lrow * 64 + quad * 8);
    const bf16x8 k1 = *(const bf16x8*)(base + 1024 + lrow * 64 + 32 + quad * 8);

    const floatx4 fzero = {0.f, 0.f, 0.f, 0.f};
    floatx4 e = fzero;
    e = __builtin_amdgcn_mfma_f32_16x16x32_bf16(q0, k0, e, 0, 0, 0);
    e = __builtin_amdgcn_mfma_f32_16x16x32_bf16(q1, k1, e, 0, 0, 0);
    // lane holds E[h = quad*4+r][l2 = lrow]

    #pragma unroll
    for (int r = 0; r < 4; r++) {
        float xv = e[r] * 0.03125f;   // 1/sqrt(1024)
        float mx = xv;
        mx = fmaxf(mx, __shfl_xor(mx, 1));
        mx = fmaxf(mx, __shfl_xor(mx, 2));
        mx = fmaxf(mx, __shfl_xor(mx, 4));
        mx = fmaxf(mx, __shfl_xor(mx, 8));
        float p = __expf(xv - mx);
        float s = p;
        s += __shfl_xor(s, 1);
        s += __shfl_xor(s, 2);
        s += __shfl_xor(s, 4);
        s += __shfl_xor(s, 8);
        sA[wv][(quad * 4 + r) * 32 + lrow] = f2b(p / s);
    }
    __syncthreads();

    // A-operand layout: lane holds A[m=lrow][k=quad*8+j]; quads 2,3 read zero pad
    const bf16x8 afrag = *(const bf16x8*)(&sA[wv][lrow * 32 + quad * 8]);

    bf16x8 vf[4];
    #pragma unroll
    for (int j = 0; j < 4; j++)
        #pragma unroll
        for (int jj = 0; jj < 8; jj++)
            vf[j][jj] = __builtin_bit_cast(__bf16, (u16)0);
    if (quad < 2) {
        const u16* V = base + 2048;
        #pragma unroll
        for (int j = 0; j < 4; j++)
            #pragma unroll
            for (int jj = 0; jj < 8; jj++)
                vf[j][jj] = __builtin_bit_cast(__bf16, V[(quad * 8 + jj) * 64 + j * 16 + lrow]);
    }

    const int nb = tok >> 13;     // batch within chunk
    const int sl = tok & 8191;    // position within batch
    const size_t zbase = ((size_t)nb * 8192 + (sl >> 4)) * 1024 + (size_t)(sl & 15) * 64;
    #pragma unroll
    for (int j = 0; j < 4; j++) {
        floatx4 y = __builtin_amdgcn_mfma_f32_16x16x32_bf16(afrag, vf[j], fzero, 0, 0, 0);
        #pragma unroll
        for (int r = 0; r < 4; r++)
            Z[zbase + (size_t)(quad * 4 + r) * 512 * 1024 + j * 16 + lrow] = f2b(y[r]);
    }
}

// ---------------- launch ----------------
extern "C" void kernel_launch(void* const* d_in, const int* in_sizes, int n_in,
                              void* d_out, int out_size, void* d_ws, size_t ws_size,
                              hipStream_t stream)
{
    (void)in_sizes; (void)n_in; (void)out_size;
    const float* x  = (const float*)d_in[0];
    const float* Wq = (const float*)d_in[1];
    const float* Wk = (const float*)d_in[2];
    const float* Wv = (const float*)d_in[3];
    const float* Wo = (const float*)d_in[4];
    const float* bq = (const float*)d_in[5];
    const float* bk = (const float*)d_in[6];
    const float* bv = (const float*)d_in[7];
    const float* bo = (const float*)d_in[8];

    const size_t Mtot = 32768;   // 4 * 8192 tokens
    char* ws = (char*)d_ws;
    u16*   Xbf  = (u16*)ws;                                        // 64 MB
    u16*   Wqkv = (u16*)(ws + (64ull << 20));                      // 6 MB
    u16*   Wob  = (u16*)(ws + (64ull << 20) + (6ull << 20));       // 2 MB
    float* bqkv = (float*)(ws + (72ull << 20));                    // 12 KB
    char*  dyn  = ws + (72ull << 20) + 16384;
    const size_t fixed = (72ull << 20) + 16384;

    // pick smallest batch-chunking that fits the workspace
    int c = 4;
    for (int cc = 1; cc <= 4; cc <<= 1) {
        size_t Rr = Mtot / cc;
        if (fixed + Rr * 3072 * 2 + Rr * 1024 * 2 <= ws_size) { c = cc; break; }
    }
    const size_t R = Mtot / c;
    u16* QKV = (u16*)dyn;
    u16* Zb  = (u16*)(dyn + R * 3072 * 2);

    cast_f32_bf16<<<dim3(32768), dim3(256), 0, stream>>>(x, Xbf, (int)(Mtot * 1024 / 4));
    cast_f32_bf16<<<dim3(1024),  dim3(256), 0, stream>>>(Wq, Wqkv,           262144);
    cast_f32_bf16<<<dim3(1024),  dim3(256), 0, stream>>>(Wk, Wqkv + 1048576, 262144);
    cast_f32_bf16<<<dim3(1024),  dim3(256), 0, stream>>>(Wv, Wqkv + 2097152, 262144);
    cast_f32_bf16<<<dim3(1024),  dim3(256), 0, stream>>>(Wo, Wob,            262144);
    hipMemcpyAsync(bqkv,        bq, 1024 * sizeof(float), hipMemcpyDeviceToDevice, stream);
    hipMemcpyAsync(bqkv + 1024, bk, 1024 * sizeof(float), hipMemcpyDeviceToDevice, stream);
    hipMemcpyAsync(bqkv + 2048, bv, 1024 * sizeof(float), hipMemcpyDeviceToDevice, stream);

    for (int ci = 0; ci < c; ci++) {
        const u16* Ab   = Xbf + (size_t)ci * R * 1024;
        float*     outp = (float*)d_out + (size_t)ci * R * 1024;
        gemm_bt<true ><<<dim3(3072 / 128, (unsigned)(R / 128)), dim3(256), 0, stream>>>(Ab, Wqkv, bqkv, QKV, 3072, 1024);
        attn<<<dim3((unsigned)(R / 4)), dim3(256), 0, stream>>>(QKV, Zb);
        gemm_bt<false><<<dim3(1024 / 128, (unsigned)(R / 128)), dim3(256), 0, stream>>>(Zb, Wob, bo, outp, 1024, 1024);
    }
}

// Round 2
// 621.041 us; speedup vs baseline: 1.0441x; 1.0441x over previous
//
#include <hip/hip_runtime.h>
#include <cstdint>
#include <cstddef>

typedef unsigned short u16;
typedef __attribute__((ext_vector_type(8))) __bf16 bf16x8;
typedef __attribute__((ext_vector_type(4))) float floatx4;

typedef const __attribute__((address_space(1))) void* gptr_t;
typedef __attribute__((address_space(3))) void* lptr_t;

__device__ __forceinline__ u16 f2b(float f) {
    unsigned u = __builtin_bit_cast(unsigned, f);
    u += 0x7fffu + ((u >> 16) & 1u);   // RNE; inputs are finite
    return (u16)(u >> 16);
}

// ---------------- fp32 -> bf16 cast (vectorized) ----------------
__global__ void cast_f32_bf16(const float* __restrict__ in, u16* __restrict__ out, int n4) {
    int i = blockIdx.x * blockDim.x + threadIdx.x;
    if (i < n4) {
        const float4 v = ((const float4*)in)[i];
        ushort4 o;
        o.x = f2b(v.x); o.y = f2b(v.y); o.z = f2b(v.z); o.w = f2b(v.w);
        ((ushort4*)out)[i] = o;
    }
}

// ---------------- bf16 GEMM, C = A @ B^T + bias ----------------
// (unchanged m97-style structure; known plateau ~770 TF at this shape)
template <bool OUT_BF16>
__global__ __launch_bounds__(256, 2)
void gemm_bt(const u16* __restrict__ A, const u16* __restrict__ B,
             const float* __restrict__ bias, void* __restrict__ Cout,
             int N, int K)
{
    __shared__ u16 lA[128 * 32];
    __shared__ u16 lB[128 * 32];

    const int tid  = threadIdx.x;
    const int m0   = blockIdx.y * 128;
    const int n0   = blockIdx.x * 128;
    const int row  = tid >> 2;
    const int chk  = tid & 3;
    const int lane = tid & 63;
    const int wv   = tid >> 6;
    const int wm   = wv >> 1;
    const int wn   = wv & 1;
    const int lrow = lane & 15;
    const int quad = lane >> 4;

    const u16* gA0 = A + (size_t)(m0 + row) * K + chk * 8;
    const u16* gB0 = B + (size_t)(n0 + row) * K + chk * 8;
    u16* sA0 = lA + tid * 8;
    u16* sB0 = lB + tid * 8;

    const u16* pA = lA + (wm * 64 + lrow) * 32 + quad * 8;
    const u16* pB = lB + (wn * 64 + lrow) * 32 + quad * 8;

    const floatx4 fzero = {0.f, 0.f, 0.f, 0.f};
    floatx4 acc[4][4];
    #pragma unroll
    for (int i = 0; i < 4; i++)
        #pragma unroll
        for (int j = 0; j < 4; j++) acc[i][j] = fzero;

    const size_t rstride = (size_t)64 * K;

    for (int k0 = 0; k0 < K; k0 += 32) {
        __builtin_amdgcn_global_load_lds((gptr_t)(gA0 + k0),           (lptr_t)sA0,          16, 0, 0);
        __builtin_amdgcn_global_load_lds((gptr_t)(gA0 + rstride + k0), (lptr_t)(sA0 + 2048), 16, 0, 0);
        __builtin_amdgcn_global_load_lds((gptr_t)(gB0 + k0),           (lptr_t)sB0,          16, 0, 0);
        __builtin_amdgcn_global_load_lds((gptr_t)(gB0 + rstride + k0), (lptr_t)(sB0 + 2048), 16, 0, 0);
        __syncthreads();

        bf16x8 af[4], bfr[4];
        #pragma unroll
        for (int i = 0; i < 4; i++) {
            af[i]  = *(const bf16x8*)(pA + i * 512);
            bfr[i] = *(const bf16x8*)(pB + i * 512);
        }
        #pragma unroll
        for (int i = 0; i < 4; i++)
            #pragma unroll
            for (int j = 0; j < 4; j++)
                acc[i][j] = __builtin_amdgcn_mfma_f32_16x16x32_bf16(af[i], bfr[j], acc[i][j], 0, 0, 0);
        __syncthreads();
    }

    float bsv[4];
    #pragma unroll
    for (int j = 0; j < 4; j++) bsv[j] = bias[n0 + wn * 64 + j * 16 + lrow];

    #pragma unroll
    for (int i = 0; i < 4; i++) {
        const int mbase = m0 + wm * 64 + i * 16 + quad * 4;
        #pragma unroll
        for (int j = 0; j < 4; j++) {
            const int n = n0 + wn * 64 + j * 16 + lrow;
            #pragma unroll
            for (int r = 0; r < 4; r++) {
                const float v = acc[i][j][r] + bsv[j];
                const size_t idx = (size_t)(mbase + r) * N + n;
                if constexpr (OUT_BF16) ((u16*)Cout)[idx] = f2b(v);
                else                    ((float*)Cout)[idx] = v;
            }
        }
    }
}

// ---------------- attention v2: 16 tokens / block ----------------
// 4 waves x 4 tokens. Per token (wave-private, no barriers):
//   Q,K frags: direct vectorized global loads -> E = q@k^T (2 MFMA)
//   softmax over 16-lane groups via shuffles -> A staged in per-wave LDS
//   V: bf16x8 global loads -> LDS transpose (bit-swizzled rows, conflict-free
//      ds_write_b32) -> B-frags via ds_read_b128
//   Y = A@V (4 MFMA) -> staged in sY[t][h][72]
// Then one barrier; block writes 16 complete 2KB Z rows fully coalesced.
__global__ __launch_bounds__(256)
void attn(const u16* __restrict__ QKV, u16* __restrict__ Z)
{
    __shared__ __align__(16) u16 sV[4][1024];     // per-wave V^T, phys_row=(d&7)*8+(d>>3), 16 l per row
    __shared__ __align__(16) u16 sA[4][640];      // per-wave A, rows of 40 el (k=16..31 zeroed)
    __shared__ __align__(16) u16 sY[16 * 1152];   // [t][h][72]

    const int tid  = threadIdx.x;
    const int lane = tid & 63;
    const int wv   = tid >> 6;
    const int lrow = lane & 15;
    const int quad = lane >> 4;
    const int pp   = lane >> 3;   // l-pair 0..7
    const int cc   = lane & 7;    // d-chunk 0..7

    // zero the k=16..31 pad of sA (per wave, once; persists across tokens)
    #pragma unroll
    for (int i = 0; i < 4; i++) {
        const int idx = i * 64 + lane;           // 0..255
        sA[wv][(idx >> 4) * 40 + 16 + (idx & 15)] = 0;
    }

    const int tgrp = blockIdx.x * 16;            // chunk-relative first token
    const int nb   = tgrp >> 13;
    const int sg   = (tgrp & 8191) >> 4;

    const floatx4 fzero = {0.f, 0.f, 0.f, 0.f};

    for (int tt = 0; tt < 4; tt++) {
        const int t = wv * 4 + tt;
        const u16* base = QKV + (size_t)(tgrp + t) * 3072;

        const bf16x8 q0 = *(const bf16x8*)(base + lrow * 64      + quad * 8);
        const bf16x8 q1 = *(const bf16x8*)(base + lrow * 64 + 32 + quad * 8);
        const bf16x8 k0 = *(const bf16x8*)(base + 1024 + lrow * 64      + quad * 8);
        const bf16x8 k1 = *(const bf16x8*)(base + 1024 + lrow * 64 + 32 + quad * 8);

        // V load (rows 2p, 2p+1; cols cc*8..cc*8+7) + transpose into sV[wv]
        const u16* V = base + 2048;
        const bf16x8 va = *(const bf16x8*)(V + (2 * pp)     * 64 + cc * 8);
        const bf16x8 vb = *(const bf16x8*)(V + (2 * pp + 1) * 64 + cc * 8);
        #pragma unroll
        for (int s = 0; s < 8; s++) {
            const unsigned pv = (unsigned)__builtin_bit_cast(u16, (__bf16)va[s]) |
                                ((unsigned)__builtin_bit_cast(u16, (__bf16)vb[s]) << 16);
            // logical d = cc*8+s -> phys_row = s*8+cc ; col l = 2*pp
            *(unsigned*)&sV[wv][(s * 8 + cc) * 16 + 2 * pp] = pv;
        }

        floatx4 e = fzero;
        e = __builtin_amdgcn_mfma_f32_16x16x32_bf16(q0, k0, e, 0, 0, 0);
        e = __builtin_amdgcn_mfma_f32_16x16x32_bf16(q1, k1, e, 0, 0, 0);

        #pragma unroll
        for (int r = 0; r < 4; r++) {
            const float xv = e[r] * 0.03125f;    // 1/sqrt(1024)
            float mx = xv;
            mx = fmaxf(mx, __shfl_xor(mx, 1));
            mx = fmaxf(mx, __shfl_xor(mx, 2));
            mx = fmaxf(mx, __shfl_xor(mx, 4));
            mx = fmaxf(mx, __shfl_xor(mx, 8));
            const float p = __expf(xv - mx);
            float s = p;
            s += __shfl_xor(s, 1);
            s += __shfl_xor(s, 2);
            s += __shfl_xor(s, 4);
            s += __shfl_xor(s, 8);
            sA[wv][(quad * 4 + r) * 40 + lrow] = f2b(p / s);
        }

        const bf16x8 af = *(const bf16x8*)&sA[wv][lrow * 40 + quad * 8];

        // B-frags: quads 0,1 read V^T; quads 2,3 stay zero (A pad is zero too)
        bf16x8 bfr[4];
        #pragma unroll
        for (int j = 0; j < 4; j++)
            #pragma unroll
            for (int jj = 0; jj < 8; jj++)
                bfr[j][jj] = __builtin_bit_cast(__bf16, (u16)0);
        if (quad < 2) {
            #pragma unroll
            for (int j = 0; j < 4; j++) {
                const int pr = (lrow & 7) * 8 + j * 2 + (lrow >> 3);  // phys_row of d=j*16+lrow
                bfr[j] = *(const bf16x8*)&sV[wv][pr * 16 + quad * 8];
            }
        }

        #pragma unroll
        for (int j = 0; j < 4; j++) {
            const floatx4 y = __builtin_amdgcn_mfma_f32_16x16x32_bf16(af, bfr[j], fzero, 0, 0, 0);
            #pragma unroll
            for (int r = 0; r < 4; r++)
                sY[t * 1152 + (quad * 4 + r) * 72 + j * 16 + lrow] = f2b(y[r]);
        }
    }

    __syncthreads();

    // write 16 complete Z rows (h*512+sg), each 2KB contiguous
    const int h   = tid >> 4;
    const int pos = tid & 15;
    u16* zrow = Z + (size_t)(nb * 8192 + h * 512 + sg) * 1024;
    #pragma unroll
    for (int it = 0; it < 8; it++) {
        const int c16 = it * 16 + pos;          // 0..127 ; col chunk = c16*8 elements
        const int t = c16 >> 3, dc = c16 & 7;
        const uint4 v = *(const uint4*)&sY[t * 1152 + h * 72 + dc * 8];
        *(uint4*)(zrow + c16 * 8) = v;
    }
}

// ---------------- launch ----------------
extern "C" void kernel_launch(void* const* d_in, const int* in_sizes, int n_in,
                              void* d_out, int out_size, void* d_ws, size_t ws_size,
                              hipStream_t stream)
{
    (void)in_sizes; (void)n_in; (void)out_size;
    const float* x  = (const float*)d_in[0];
    const float* Wq = (const float*)d_in[1];
    const float* Wk = (const float*)d_in[2];
    const float* Wv = (const float*)d_in[3];
    const float* Wo = (const float*)d_in[4];
    const float* bq = (const float*)d_in[5];
    const float* bk = (const float*)d_in[6];
    const float* bv = (const float*)d_in[7];
    const float* bo = (const float*)d_in[8];

    const size_t Mtot = 32768;   // 4 * 8192 tokens
    char* ws = (char*)d_ws;
    u16*   Xbf  = (u16*)ws;                                        // 64 MB
    u16*   Wqkv = (u16*)(ws + (64ull << 20));                      // 6 MB
    u16*   Wob  = (u16*)(ws + (64ull << 20) + (6ull << 20));       // 2 MB
    float* bqkv = (float*)(ws + (72ull << 20));                    // 12 KB
    char*  dyn  = ws + (72ull << 20) + 16384;
    const size_t fixed = (72ull << 20) + 16384;

    int c = 4;
    for (int cc = 1; cc <= 4; cc <<= 1) {
        size_t Rr = Mtot / cc;
        if (fixed + Rr * 3072 * 2 + Rr * 1024 * 2 <= ws_size) { c = cc; break; }
    }
    const size_t R = Mtot / c;
    u16* QKV = (u16*)dyn;
    u16* Zb  = (u16*)(dyn + R * 3072 * 2);

    cast_f32_bf16<<<dim3(32768), dim3(256), 0, stream>>>(x, Xbf, (int)(Mtot * 1024 / 4));
    cast_f32_bf16<<<dim3(1024),  dim3(256), 0, stream>>>(Wq, Wqkv,           262144);
    cast_f32_bf16<<<dim3(1024),  dim3(256), 0, stream>>>(Wk, Wqkv + 1048576, 262144);
    cast_f32_bf16<<<dim3(1024),  dim3(256), 0, stream>>>(Wv, Wqkv + 2097152, 262144);
    cast_f32_bf16<<<dim3(1024),  dim3(256), 0, stream>>>(Wo, Wob,            262144);
    hipMemcpyAsync(bqkv,        bq, 1024 * sizeof(float), hipMemcpyDeviceToDevice, stream);
    hipMemcpyAsync(bqkv + 1024, bk, 1024 * sizeof(float), hipMemcpyDeviceToDevice, stream);
    hipMemcpyAsync(bqkv + 2048, bv, 1024 * sizeof(float), hipMemcpyDeviceToDevice, stream);

    for (int ci = 0; ci < c; ci++) {
        const u16* Ab   = Xbf + (size_t)ci * R * 1024;
        float*     outp = (float*)d_out + (size_t)ci * R * 1024;
        gemm_bt<true ><<<dim3(3072 / 128, (unsigned)(R / 128)), dim3(256), 0, stream>>>(Ab, Wqkv, bqkv, QKV, 3072, 1024);
        attn<<<dim3((unsigned)(R / 16)), dim3(256), 0, stream>>>(QKV, Zb);
        gemm_bt<false><<<dim3(1024 / 128, (unsigned)(R / 128)), dim3(256), 0, stream>>>(Zb, Wob, bo, outp, 1024, 1024);
    }
}

// Round 3
// 614.997 us; speedup vs baseline: 1.0544x; 1.0098x over previous
//
#include <hip/hip_runtime.h>
#include <cstdint>
#include <cstddef>

typedef unsigned short u16;
typedef __attribute__((ext_vector_type(8))) __bf16 bf16x8;
typedef __attribute__((ext_vector_type(4))) float floatx4;

typedef const __attribute__((address_space(1))) void* gptr_t;
typedef __attribute__((address_space(3))) void* lptr_t;

__device__ __forceinline__ u16 f2b(float f) {
    unsigned u = __builtin_bit_cast(unsigned, f);
    u += 0x7fffu + ((u >> 16) & 1u);   // RNE; inputs are finite
    return (u16)(u >> 16);
}

// DPP row (16-lane) rotate-reductions — VALU pipe, no DS traffic.
template <int N>
__device__ __forceinline__ float ror_add(float x) {
    int y = __builtin_amdgcn_update_dpp(0, __builtin_bit_cast(int, x), 0x120 + N, 0xF, 0xF, true);
    return x + __builtin_bit_cast(float, y);
}
template <int N>
__device__ __forceinline__ float ror_max(float x) {
    int y = __builtin_amdgcn_update_dpp(0, __builtin_bit_cast(int, x), 0x120 + N, 0xF, 0xF, true);
    return fmaxf(x, __builtin_bit_cast(float, y));
}

// ---------------- fp32 -> bf16 casts ----------------
__global__ void cast_x(const float* __restrict__ in, u16* __restrict__ out, int n4) {
    const int stride = gridDim.x * blockDim.x;
    for (int i = blockIdx.x * blockDim.x + threadIdx.x; i < n4; i += stride) {
        const float4 v = ((const float4*)in)[i];
        ushort4 o;
        o.x = f2b(v.x); o.y = f2b(v.y); o.z = f2b(v.z); o.w = f2b(v.w);
        ((ushort4*)out)[i] = o;
    }
}

// All four 1024x1024 weights in one kernel. Wqkv gets Wq|Wk|Wv, Wob gets Wo.
__global__ void cast_w(const float* __restrict__ Wq, const float* __restrict__ Wk,
                       const float* __restrict__ Wv, const float* __restrict__ Wo,
                       u16* __restrict__ Wqkv, u16* __restrict__ Wob) {
    const int stride = gridDim.x * blockDim.x;
    for (int i = blockIdx.x * blockDim.x + threadIdx.x; i < 1048576; i += stride) {
        const int which = i >> 18;          // 262144 float4 per matrix
        const int local = i & 0x3FFFF;
        const float* src = which == 0 ? Wq : which == 1 ? Wk : which == 2 ? Wv : Wo;
        const float4 v = ((const float4*)src)[local];
        ushort4 o;
        o.x = f2b(v.x); o.y = f2b(v.y); o.z = f2b(v.z); o.w = f2b(v.w);
        ushort4* dst = which < 3 ? (ushort4*)Wqkv + which * 262144 + local
                                 : (ushort4*)Wob + local;
        *dst = o;
    }
}

// ---------------- bf16 GEMM body, C = A @ B^T + bias ----------------
// bias selected per output column from three 1024-length vectors.
template <bool OUT_BF16>
__device__ __forceinline__
void gemm_body(const u16* __restrict__ A, const u16* __restrict__ B,
               const float* __restrict__ b0, const float* __restrict__ b1,
               const float* __restrict__ b2, void* __restrict__ Cout,
               int N, int K)
{
    __shared__ u16 lA[128 * 32];
    __shared__ u16 lB[128 * 32];

    const int tid  = threadIdx.x;
    const int m0   = blockIdx.y * 128;
    const int n0   = blockIdx.x * 128;
    const int row  = tid >> 2;
    const int chk  = tid & 3;
    const int lane = tid & 63;
    const int wv   = tid >> 6;
    const int wm   = wv >> 1;
    const int wn   = wv & 1;
    const int lrow = lane & 15;
    const int quad = lane >> 4;

    const u16* gA0 = A + (size_t)(m0 + row) * K + chk * 8;
    const u16* gB0 = B + (size_t)(n0 + row) * K + chk * 8;
    u16* sA0 = lA + tid * 8;
    u16* sB0 = lB + tid * 8;

    const u16* pA = lA + (wm * 64 + lrow) * 32 + quad * 8;
    const u16* pB = lB + (wn * 64 + lrow) * 32 + quad * 8;

    const floatx4 fzero = {0.f, 0.f, 0.f, 0.f};
    floatx4 acc[4][4];
    #pragma unroll
    for (int i = 0; i < 4; i++)
        #pragma unroll
        for (int j = 0; j < 4; j++) acc[i][j] = fzero;

    const size_t rstride = (size_t)64 * K;

    for (int k0 = 0; k0 < K; k0 += 32) {
        __builtin_amdgcn_global_load_lds((gptr_t)(gA0 + k0),           (lptr_t)sA0,          16, 0, 0);
        __builtin_amdgcn_global_load_lds((gptr_t)(gA0 + rstride + k0), (lptr_t)(sA0 + 2048), 16, 0, 0);
        __builtin_amdgcn_global_load_lds((gptr_t)(gB0 + k0),           (lptr_t)sB0,          16, 0, 0);
        __builtin_amdgcn_global_load_lds((gptr_t)(gB0 + rstride + k0), (lptr_t)(sB0 + 2048), 16, 0, 0);
        __syncthreads();

        bf16x8 af[4], bfr[4];
        #pragma unroll
        for (int i = 0; i < 4; i++) {
            af[i]  = *(const bf16x8*)(pA + i * 512);
            bfr[i] = *(const bf16x8*)(pB + i * 512);
        }
        #pragma unroll
        for (int i = 0; i < 4; i++)
            #pragma unroll
            for (int j = 0; j < 4; j++)
                acc[i][j] = __builtin_amdgcn_mfma_f32_16x16x32_bf16(af[i], bfr[j], acc[i][j], 0, 0, 0);
        __syncthreads();
    }

    float bsv[4];
    #pragma unroll
    for (int j = 0; j < 4; j++) {
        const int n = n0 + wn * 64 + j * 16 + lrow;
        const float* bp = n < 1024 ? b0 : (n < 2048 ? b1 : b2);
        bsv[j] = bp[n & 1023];
    }

    #pragma unroll
    for (int i = 0; i < 4; i++) {
        const int mbase = m0 + wm * 64 + i * 16 + quad * 4;
        #pragma unroll
        for (int j = 0; j < 4; j++) {
            const int n = n0 + wn * 64 + j * 16 + lrow;
            #pragma unroll
            for (int r = 0; r < 4; r++) {
                const float v = acc[i][j][r] + bsv[j];
                const size_t idx = (size_t)(mbase + r) * N + n;
                if constexpr (OUT_BF16) ((u16*)Cout)[idx] = f2b(v);
                else                    ((float*)Cout)[idx] = v;
            }
        }
    }
}

__global__ __launch_bounds__(256, 2)
void gemm_qkv(const u16* __restrict__ A, const u16* __restrict__ B,
              const float* __restrict__ b0, const float* __restrict__ b1,
              const float* __restrict__ b2, u16* __restrict__ C, int N, int K)
{ gemm_body<true>(A, B, b0, b1, b2, (void*)C, N, K); }

__global__ __launch_bounds__(256, 2)
void gemm_out(const u16* __restrict__ A, const u16* __restrict__ B,
              const float* __restrict__ b0, float* __restrict__ C, int N, int K)
{ gemm_body<false>(A, B, b0, b0, b0, (void*)C, N, K); }

// ---------------- attention v3: DPP softmax ----------------
// 4 waves x 4 tokens per block, wave-private token pipeline, one barrier,
// coalesced block write-out of 16 complete 2KB Z rows.
__global__ __launch_bounds__(256)
void attn_v3(const u16* __restrict__ QKV, u16* __restrict__ Z)
{
    __shared__ __align__(16) u16 sV[4][1024];     // per-wave V^T, phys_row=(d&7)*8+(d>>3)
    __shared__ __align__(16) u16 sA[4][640];      // per-wave A, rows of 40 (k=16..31 zeroed)
    __shared__ __align__(16) u16 sY[16 * 1152];   // [t][h][72]

    const int tid  = threadIdx.x;
    const int lane = tid & 63;
    const int wv   = tid >> 6;
    const int lrow = lane & 15;
    const int quad = lane >> 4;
    const int pp   = lane >> 3;   // l-pair 0..7
    const int cc   = lane & 7;    // d-chunk 0..7

    // zero the k=16..31 pad of sA (per wave, once; persists across tokens)
    #pragma unroll
    for (int i = 0; i < 4; i++) {
        const int idx = i * 64 + lane;
        sA[wv][(idx >> 4) * 40 + 16 + (idx & 15)] = 0;
    }

    const int tgrp = blockIdx.x * 16;
    const int nb   = tgrp >> 13;
    const int sg   = (tgrp & 8191) >> 4;

    const floatx4 fzero = {0.f, 0.f, 0.f, 0.f};

    for (int tt = 0; tt < 4; tt++) {
        const int t = wv * 4 + tt;
        const u16* base = QKV + (size_t)(tgrp + t) * 3072;

        const bf16x8 q0 = *(const bf16x8*)(base + lrow * 64      + quad * 8);
        const bf16x8 q1 = *(const bf16x8*)(base + lrow * 64 + 32 + quad * 8);
        const bf16x8 k0 = *(const bf16x8*)(base + 1024 + lrow * 64      + quad * 8);
        const bf16x8 k1 = *(const bf16x8*)(base + 1024 + lrow * 64 + 32 + quad * 8);

        // V load + transpose into per-wave LDS (conflict-free b32 writes)
        const u16* V = base + 2048;
        const bf16x8 va = *(const bf16x8*)(V + (2 * pp)     * 64 + cc * 8);
        const bf16x8 vb = *(const bf16x8*)(V + (2 * pp + 1) * 64 + cc * 8);
        #pragma unroll
        for (int s = 0; s < 8; s++) {
            const unsigned pv = (unsigned)__builtin_bit_cast(u16, (__bf16)va[s]) |
                                ((unsigned)__builtin_bit_cast(u16, (__bf16)vb[s]) << 16);
            *(unsigned*)&sV[wv][(s * 8 + cc) * 16 + 2 * pp] = pv;
        }

        floatx4 e = fzero;
        e = __builtin_amdgcn_mfma_f32_16x16x32_bf16(q0, k0, e, 0, 0, 0);
        e = __builtin_amdgcn_mfma_f32_16x16x32_bf16(q1, k1, e, 0, 0, 0);

        // softmax over l (= the 16 lanes of this quad's DPP row), pure VALU
        #pragma unroll
        for (int r = 0; r < 4; r++) {
            const float xv = e[r] * 0.03125f;    // 1/sqrt(1024)
            float mx = xv;
            mx = ror_max<1>(mx); mx = ror_max<2>(mx);
            mx = ror_max<4>(mx); mx = ror_max<8>(mx);
            const float p = __expf(xv - mx);
            float s = p;
            s = ror_add<1>(s); s = ror_add<2>(s);
            s = ror_add<4>(s); s = ror_add<8>(s);
            sA[wv][(quad * 4 + r) * 40 + lrow] = f2b(p * __builtin_amdgcn_rcpf(s));
        }

        const bf16x8 af = *(const bf16x8*)&sA[wv][lrow * 40 + quad * 8];

        bf16x8 bfr[4];
        #pragma unroll
        for (int j = 0; j < 4; j++)
            #pragma unroll
            for (int jj = 0; jj < 8; jj++)
                bfr[j][jj] = __builtin_bit_cast(__bf16, (u16)0);
        if (quad < 2) {
            #pragma unroll
            for (int j = 0; j < 4; j++) {
                const int pr = (lrow & 7) * 8 + j * 2 + (lrow >> 3);
                bfr[j] = *(const bf16x8*)&sV[wv][pr * 16 + quad * 8];
            }
        }

        #pragma unroll
        for (int j = 0; j < 4; j++) {
            const floatx4 y = __builtin_amdgcn_mfma_f32_16x16x32_bf16(af, bfr[j], fzero, 0, 0, 0);
            #pragma unroll
            for (int r = 0; r < 4; r++)
                sY[t * 1152 + (quad * 4 + r) * 72 + j * 16 + lrow] = f2b(y[r]);
        }
    }

    __syncthreads();

    // write 16 complete Z rows (h*512+sg), each 2KB contiguous
    const int h   = tid >> 4;
    const int pos = tid & 15;
    u16* zrow = Z + (size_t)(nb * 8192 + h * 512 + sg) * 1024;
    #pragma unroll
    for (int it = 0; it < 8; it++) {
        const int c16 = it * 16 + pos;
        const int t = c16 >> 3, dc = c16 & 7;
        const uint4 v = *(const uint4*)&sY[t * 1152 + h * 72 + dc * 8];
        *(uint4*)(zrow + c16 * 8) = v;
    }
}

// ---------------- launch ----------------
extern "C" void kernel_launch(void* const* d_in, const int* in_sizes, int n_in,
                              void* d_out, int out_size, void* d_ws, size_t ws_size,
                              hipStream_t stream)
{
    (void)in_sizes; (void)n_in; (void)out_size;
    const float* x  = (const float*)d_in[0];
    const float* Wq = (const float*)d_in[1];
    const float* Wk = (const float*)d_in[2];
    const float* Wv = (const float*)d_in[3];
    const float* Wo = (const float*)d_in[4];
    const float* bq = (const float*)d_in[5];
    const float* bk = (const float*)d_in[6];
    const float* bv = (const float*)d_in[7];
    const float* bo = (const float*)d_in[8];

    const size_t Mtot = 32768;   // 4 * 8192 tokens
    char* ws = (char*)d_ws;
    u16* Xbf  = (u16*)ws;                                   // 64 MB
    u16* Wqkv = (u16*)(ws + (64ull << 20));                 // 6 MB
    u16* Wob  = (u16*)(ws + (64ull << 20) + (6ull << 20));  // 2 MB
    char* dyn = ws + (72ull << 20);
    const size_t fixed = (72ull << 20);

    int c = 4;
    for (int cc = 1; cc <= 4; cc <<= 1) {
        size_t Rr = Mtot / cc;
        if (fixed + Rr * 3072 * 2 + Rr * 1024 * 2 <= ws_size) { c = cc; break; }
    }
    const size_t R = Mtot / c;
    u16* QKV = (u16*)dyn;
    u16* Zb  = (u16*)(dyn + R * 3072 * 2);

    cast_x<<<dim3(4096), dim3(256), 0, stream>>>(x, Xbf, (int)(Mtot * 1024 / 4));
    cast_w<<<dim3(1024), dim3(256), 0, stream>>>(Wq, Wk, Wv, Wo, Wqkv, Wob);

    for (int ci = 0; ci < c; ci++) {
        const u16* Ab   = Xbf + (size_t)ci * R * 1024;
        float*     outp = (float*)d_out + (size_t)ci * R * 1024;
        gemm_qkv<<<dim3(24, (unsigned)(R / 128)), dim3(256), 0, stream>>>(Ab, Wqkv, bq, bk, bv, QKV, 3072, 1024);
        attn_v3<<<dim3((unsigned)(R / 16)), dim3(256), 0, stream>>>(QKV, Zb);
        gemm_out<<<dim3(8, (unsigned)(R / 128)), dim3(256), 0, stream>>>(Zb, Wob, bo, outp, 1024, 1024);
    }
}